// Round 8
// baseline (123.230 us; speedup 1.0000x reference)
//
#include <hip/hip_runtime.h>
#include <math.h>

// Problem constants (fixed by setup_inputs)
#define NL 4          // n_latents
#define MM 1024       // codebook entries per latent
#define DD 16         // dim per latent
#define PP 16384      // points = N*H*W
#define PLANE 1024    // H*W
#define NSTRIDE 65536 // z_dim*H*W
#define CHUNK 256     // points per workgroup (quarter plane)
#define NCHUNK (PP / CHUNK)   // 64
#define MGROUP 256    // codes per workgroup (4 waves x 2 strips x 32)
#define NMG (MM / MGROUP)     // 4
#define GRID (NL * NMG * NCHUNK) // 1024
#define ZSTR 20       // LDS stride per point in f16 units (16 data + 4 pad = 40B)
#define SCR_STRIDE 33 // f32 words per row in the transpose-reduce scratch (conflict-free)
#define SCR_WAVE 1056 // 32*33 words per wave region

// Schraudolph-style fast 2^x: bitcast(u32(2^23*(x + B))), B = 127 - 0.0353
// (minimax-centered, max rel err ~±3.5%). x <= 0 always here; negative
// 2^23*(x+B) clamps to 0 via v_cvt_u32_f32 => exact flush-to-zero underflow.
#define EXP2_SCALE 8388608.0f            // 2^23
#define EXP2_BIAS  126.9647f             // 127 - sigma*

typedef _Float16 half4v  __attribute__((ext_vector_type(4)));
typedef _Float16 half8v  __attribute__((ext_vector_type(8)));
typedef float    float16v __attribute__((ext_vector_type(16)));

// Fused kernel (2 dispatches total: 16KB memset + this).
// Main loop identical to r7 (unroll 2 — r4's regression came from unroll-4 spills).
// Epilogue: per-wave LDS transpose-reduce -> atomicAdd into S (device coherence
// point), __threadfence() release, done-counter; the last block re-reads S with
// agent-scope relaxed atomic loads (bypass non-coherent L1/L2, fully pipelined),
// takes logs, reduces, writes the scalar.
// MFMA 32x32 C/D layout (HW-verified): col=lane&31, row=(reg&3)+8*(reg>>2)+4*(lane>>5)
// A layout (verified rounds 1-7, absmax=0): A[row=lane&31][k=(lane>>5)*8+j]; B same on cols.
__global__ __launch_bounds__(256, 4)
void latent_fused_kernel(const float* __restrict__ z, const float* __restrict__ e,
                         const float* __restrict__ log_sigma,
                         float* __restrict__ S, unsigned* __restrict__ done_cnt,
                         float* __restrict__ out)
{
    const int t    = threadIdx.x;
    const int lane = t & 63;
    const int wave = t >> 6;
    const int ln31 = lane & 31;
    const int hf   = lane >> 5;

    const int bid = blockIdx.x;
    const int c   = bid & (NCHUNK - 1);       // p-chunk
    const int mg  = (bid >> 6) & (NMG - 1);   // m-group
    const int l   = bid >> 8;                 // latent

    const float ls    = log_sigma[0];
    const float alpha = -0.5f * __expf(-2.0f * ls);
    const float a2    = alpha * 1.44269504088896340736f; // alpha/ln2
    const float m2a2  = -2.0f * a2;

    // zh (staging, 10240B) and scr (transpose-reduce, 16896B) share storage:
    // scr is only used after the main loop's barrier.
    __shared__ __attribute__((aligned(16))) char smem[4 * SCR_WAVE * 4];
    _Float16* zh  = (_Float16*)smem;
    float*    scr = (float*)smem;
    __shared__ float azqs[CHUNK];   // (a2*zsq + EXP2_BIAS) * 2^23  (magic form)
    __shared__ float esqs[MGROUP];
    __shared__ unsigned s_last;
    __shared__ float red[4];

    // ---- Stage z chunk: one point per thread, 16 global f32 (coalesced) -> LDS f16.
    const int n  = c >> 2;                 // 4 chunks per plane
    const int q0 = (c & 3) * CHUNK;
    const float* zb = z + (size_t)n * NSTRIDE + (size_t)l * DD * PLANE + q0;

    float sq = 0.f;
#pragma unroll
    for (int dp = 0; dp < 8; ++dp) {
        float v0 = zb[(2 * dp)     * PLANE + t];
        float v1 = zb[(2 * dp + 1) * PLANE + t];
        sq += v0 * v0 + v1 * v1;
        union { _Float16 h[2]; unsigned u; } pk;
        pk.h[0] = (_Float16)v0; pk.h[1] = (_Float16)v1;
        *(unsigned*)(&zh[t * ZSTR + 2 * dp]) = pk.u; // 4B-aligned packed store
    }
    azqs[t] = (sq * a2 + EXP2_BIAS) * EXP2_SCALE;

    // ---- A fragments for the wave's 2 strips (pre-scaled by m2a2) + exact f32 esq.
    const int m0 = mg * MGROUP + wave * 64;
    half8v Af[2];
#pragma unroll
    for (int s = 0; s < 2; ++s) {
        const float* eb = e + ((size_t)l * MM + m0 + s * 32 + ln31) * DD + hf * 8;
        float4 a0 = *(const float4*)eb;
        float4 a1 = *(const float4*)(eb + 4);
        float esq_p = a0.x*a0.x + a0.y*a0.y + a0.z*a0.z + a0.w*a0.w
                    + a1.x*a1.x + a1.y*a1.y + a1.z*a1.z + a1.w*a1.w;
        esq_p += __shfl_xor(esq_p, 32, 64);       // combine the two k-halves
        esqs[wave * 64 + s * 32 + ln31] = esq_p;  // both halves write same value
        Af[s][0] = (_Float16)(a0.x * m2a2); Af[s][1] = (_Float16)(a0.y * m2a2);
        Af[s][2] = (_Float16)(a0.z * m2a2); Af[s][3] = (_Float16)(a0.w * m2a2);
        Af[s][4] = (_Float16)(a1.x * m2a2); Af[s][5] = (_Float16)(a1.y * m2a2);
        Af[s][6] = (_Float16)(a1.z * m2a2); Af[s][7] = (_Float16)(a1.w * m2a2);
    }

    __syncthreads();

    // C operands = a2*esq[row(r)]: folded into the MFMA, constant over the p-loop.
    float16v biasC[2];
#pragma unroll
    for (int s = 0; s < 2; ++s)
#pragma unroll
        for (int r = 0; r < 16; ++r) {
            const int row = (r & 3) + 8 * (r >> 2) + 4 * hf;
            biasC[s][r] = esqs[wave * 64 + s * 32 + row] * a2;
        }

    float16v acc[2];
#pragma unroll
    for (int s = 0; s < 2; ++s)
#pragma unroll
        for (int r = 0; r < 16; ++r) acc[s][r] = 0.f;

    const _Float16* zrow = zh + ln31 * ZSTR + hf * 8;
#pragma unroll 2
    for (int pt = 0; pt < CHUNK / 32; ++pt) {
        const float az = azqs[pt * 32 + ln31];           // ds_read_b32 (broadcast), magic form
        const _Float16* bp = zrow + pt * 32 * ZSTR;
        half4v b0 = *(const half4v*)bp;                  // ds_read_b64 x2, shared by both strips
        half4v b1 = *(const half4v*)(bp + 4);
        half8v Bf = __builtin_shufflevector(b0, b1, 0, 1, 2, 3, 4, 5, 6, 7);
        float16v dd0 = __builtin_amdgcn_mfma_f32_32x32x16_f16(Af[0], Bf, biasC[0], 0, 0, 0);
        float16v dd1 = __builtin_amdgcn_mfma_f32_32x32x16_f16(Af[1], Bf, biasC[1], 0, 0, 0);
#pragma unroll
        for (int r = 0; r < 16; ++r) {
            // fast 2^(dd+az'): v_fma_f32 + v_cvt_u32_f32 (neg->0) + v_add_f32
            float u0 = fmaf(dd0[r], EXP2_SCALE, az);
            acc[0][r] += __uint_as_float(__float2uint_rz(u0));
            float u1 = fmaf(dd1[r], EXP2_SCALE, az);
            acc[1][r] += __uint_as_float(__float2uint_rz(u1));
        }
    }

    // ---- Epilogue: per-wave transpose-reduce through LDS, one pass per strip.
    __syncthreads();                        // all waves done reading zh
    float* scrw = scr + wave * SCR_WAVE;
#pragma unroll
    for (int s = 0; s < 2; ++s) {
#pragma unroll
        for (int r = 0; r < 16; ++r) {
            const int row = (r & 3) + 8 * (r >> 2) + 4 * hf;
            scrw[row * SCR_STRIDE + ln31] = acc[s][r];   // 2-way max bank alias = free
        }
        // Each lane sums half of row ln31 (16 f32), conflict-free banks (stride 33).
        const float* rp = scrw + ln31 * SCR_STRIDE + hf * 16;
        float sum = 0.f;
#pragma unroll
        for (int j = 0; j < 16; ++j) sum += rp[j];
        sum += __shfl_xor(sum, 32, 64);     // combine the two half-rows
        if (hf == 0)
            atomicAdd(&S[l * MM + m0 + s * 32 + ln31], sum); // device coherence point
        // next pass reuses scrw: DS requests from one wave are processed in order.
    }

    // ---- Last-block-done: the final block folds S -> scalar output.
    __threadfence();                 // per-wave release of its S atomics
    __syncthreads();
    if (t == 0) {
        unsigned old = atomicAdd(done_cnt, 1u);
        s_last = (old == GRID - 1) ? 1u : 0u;
    }
    __syncthreads();
    if (s_last) {
        float s = 0.f;
#pragma unroll
        for (int k = 0; k < (NL * MM) / 256; ++k) {
            // agent-scope relaxed atomic load: bypasses non-coherent L1/L2, reads
            // the same coherence point the producers' atomicAdds wrote. Independent
            // loads -> fully pipelined.
            float v = __hip_atomic_load(&S[k * 256 + t], __ATOMIC_RELAXED,
                                        __HIP_MEMORY_SCOPE_AGENT);
            s += __logf(v);
        }
#pragma unroll
        for (int off = 32; off > 0; off >>= 1) s += __shfl_down(s, off, 64);
        if ((t & 63) == 0) red[t >> 6] = s;
        __syncthreads();
        if (t == 0) {
            float tot = red[0] + red[1] + red[2] + red[3];
            out[0] = -tot / (float)(NL * MM)
                   + 32.0f * (2.0f * ls - 1.0f)   // 0.5*z_dim*(2ls-1), z_dim=64
                   + 9.70406052783923f;           // ln(16384)
        }
    }
}

extern "C" void kernel_launch(void* const* d_in, const int* in_sizes, int n_in,
                              void* d_out, int out_size, void* d_ws, size_t ws_size,
                              hipStream_t stream)
{
    const float* z  = (const float*)d_in[0];
    const float* e  = (const float*)d_in[1];
    const float* ls = (const float*)d_in[2];
    float* out = (float*)d_out;
    float* S   = (float*)d_ws;                               // 4096 f32
    unsigned* cnt = (unsigned*)((char*)d_ws + NL * MM * sizeof(float));

    // ws is re-poisoned to 0xAA before every launch; zero S + done-counter.
    hipMemsetAsync(d_ws, 0, NL * MM * sizeof(float) + 64, stream);
    latent_fused_kernel<<<GRID, 256, 0, stream>>>(z, e, ls, S, cnt, out);
}

// Round 9
// 74.210 us; speedup vs baseline: 1.6606x; 1.6606x over previous
//
#include <hip/hip_runtime.h>
#include <math.h>

// Problem constants (fixed by setup_inputs)
#define NL 4          // n_latents
#define MM 1024       // codebook entries per latent
#define DD 16         // dim per latent
#define PP 16384      // points = N*H*W
#define PLANE 1024    // H*W
#define NSTRIDE 65536 // z_dim*H*W
#define CHUNK 256     // points per workgroup (quarter plane)
#define NCHUNK (PP / CHUNK)   // 64
#define MGROUP 256    // codes per workgroup (4 waves x 2 strips x 32)
#define NMG (MM / MGROUP)     // 4
#define GRID (NL * NMG * NCHUNK) // 1024
#define ZSTR 20       // LDS stride per point in f16 units (16 data + 4 pad = 40B)
#define SCR_STRIDE 33 // f32 words per row in the transpose-reduce scratch (conflict-free)
#define SCR_WAVE 1056 // 32*33 words per wave region

// Schraudolph-style fast 2^x: bitcast(u32(2^23*(x + B))), B = 127 - 0.0353
// (minimax-centered, max rel err ~±3.5%). x <= 0 always here; negative
// 2^23*(x+B) clamps to 0 via v_cvt_u32_f32 => exact flush-to-zero underflow.
#define EXP2_SCALE 8388608.0f            // 2^23
#define EXP2_BIAS  126.9647f             // 127 - sigma*

typedef _Float16 half4v  __attribute__((ext_vector_type(4)));
typedef _Float16 half8v  __attribute__((ext_vector_type(8)));
typedef float    float16v __attribute__((ext_vector_type(16)));

// Fused kernel (2 dispatches: 16KB memset + this). Body identical to r7.
// NO __threadfence(): r8 showed per-wave device-scope release fences (L2
// writeback) serialize device-wide (~15ns each x4096 = the entire 68us).
// Correctness without it: S atomicAdds are device-scope RMWs at the device
// coherence point; __syncthreads() drains vmcnt(0) (compiler-emitted before
// s_barrier), so all adds are ACKED at the coherence point before t0 bumps
// done_cnt. The last block reads S with agent-scope relaxed atomic loads
// (bypass stale L1/per-XCD L2, fully pipelined).
// MFMA 32x32 C/D layout (HW-verified): col=lane&31, row=(reg&3)+8*(reg>>2)+4*(lane>>5)
// A layout (verified rounds 1-8, absmax=0): A[row=lane&31][k=(lane>>5)*8+j]; B same on cols.
__global__ __launch_bounds__(256, 4)
void latent_fused_kernel(const float* __restrict__ z, const float* __restrict__ e,
                         const float* __restrict__ log_sigma,
                         float* __restrict__ S, unsigned* __restrict__ done_cnt,
                         float* __restrict__ out)
{
    const int t    = threadIdx.x;
    const int lane = t & 63;
    const int wave = t >> 6;
    const int ln31 = lane & 31;
    const int hf   = lane >> 5;

    const int bid = blockIdx.x;
    const int c   = bid & (NCHUNK - 1);       // p-chunk
    const int mg  = (bid >> 6) & (NMG - 1);   // m-group
    const int l   = bid >> 8;                 // latent

    const float ls    = log_sigma[0];
    const float alpha = -0.5f * __expf(-2.0f * ls);
    const float a2    = alpha * 1.44269504088896340736f; // alpha/ln2
    const float m2a2  = -2.0f * a2;

    // zh (staging, 10240B) and scr (transpose-reduce, 16896B) share storage:
    // scr is only used after the main loop's barrier.
    __shared__ __attribute__((aligned(16))) char smem[4 * SCR_WAVE * 4];
    _Float16* zh  = (_Float16*)smem;
    float*    scr = (float*)smem;
    __shared__ float azqs[CHUNK];   // (a2*zsq + EXP2_BIAS) * 2^23  (magic form)
    __shared__ float esqs[MGROUP];
    __shared__ unsigned s_last;
    __shared__ float red[4];

    // ---- Stage z chunk: one point per thread, 16 global f32 (coalesced) -> LDS f16.
    const int n  = c >> 2;                 // 4 chunks per plane
    const int q0 = (c & 3) * CHUNK;
    const float* zb = z + (size_t)n * NSTRIDE + (size_t)l * DD * PLANE + q0;

    float sq = 0.f;
#pragma unroll
    for (int dp = 0; dp < 8; ++dp) {
        float v0 = zb[(2 * dp)     * PLANE + t];
        float v1 = zb[(2 * dp + 1) * PLANE + t];
        sq += v0 * v0 + v1 * v1;
        union { _Float16 h[2]; unsigned u; } pk;
        pk.h[0] = (_Float16)v0; pk.h[1] = (_Float16)v1;
        *(unsigned*)(&zh[t * ZSTR + 2 * dp]) = pk.u; // 4B-aligned packed store
    }
    azqs[t] = (sq * a2 + EXP2_BIAS) * EXP2_SCALE;

    // ---- A fragments for the wave's 2 strips (pre-scaled by m2a2) + exact f32 esq.
    const int m0 = mg * MGROUP + wave * 64;
    half8v Af[2];
#pragma unroll
    for (int s = 0; s < 2; ++s) {
        const float* eb = e + ((size_t)l * MM + m0 + s * 32 + ln31) * DD + hf * 8;
        float4 a0 = *(const float4*)eb;
        float4 a1 = *(const float4*)(eb + 4);
        float esq_p = a0.x*a0.x + a0.y*a0.y + a0.z*a0.z + a0.w*a0.w
                    + a1.x*a1.x + a1.y*a1.y + a1.z*a1.z + a1.w*a1.w;
        esq_p += __shfl_xor(esq_p, 32, 64);       // combine the two k-halves
        esqs[wave * 64 + s * 32 + ln31] = esq_p;  // both halves write same value
        Af[s][0] = (_Float16)(a0.x * m2a2); Af[s][1] = (_Float16)(a0.y * m2a2);
        Af[s][2] = (_Float16)(a0.z * m2a2); Af[s][3] = (_Float16)(a0.w * m2a2);
        Af[s][4] = (_Float16)(a1.x * m2a2); Af[s][5] = (_Float16)(a1.y * m2a2);
        Af[s][6] = (_Float16)(a1.z * m2a2); Af[s][7] = (_Float16)(a1.w * m2a2);
    }

    __syncthreads();

    // C operands = a2*esq[row(r)]: folded into the MFMA, constant over the p-loop.
    float16v biasC[2];
#pragma unroll
    for (int s = 0; s < 2; ++s)
#pragma unroll
        for (int r = 0; r < 16; ++r) {
            const int row = (r & 3) + 8 * (r >> 2) + 4 * hf;
            biasC[s][r] = esqs[wave * 64 + s * 32 + row] * a2;
        }

    float16v acc[2];
#pragma unroll
    for (int s = 0; s < 2; ++s)
#pragma unroll
        for (int r = 0; r < 16; ++r) acc[s][r] = 0.f;

    const _Float16* zrow = zh + ln31 * ZSTR + hf * 8;
#pragma unroll 2
    for (int pt = 0; pt < CHUNK / 32; ++pt) {
        const float az = azqs[pt * 32 + ln31];           // ds_read_b32 (broadcast), magic form
        const _Float16* bp = zrow + pt * 32 * ZSTR;
        half4v b0 = *(const half4v*)bp;                  // ds_read_b64 x2, shared by both strips
        half4v b1 = *(const half4v*)(bp + 4);
        half8v Bf = __builtin_shufflevector(b0, b1, 0, 1, 2, 3, 4, 5, 6, 7);
        float16v dd0 = __builtin_amdgcn_mfma_f32_32x32x16_f16(Af[0], Bf, biasC[0], 0, 0, 0);
        float16v dd1 = __builtin_amdgcn_mfma_f32_32x32x16_f16(Af[1], Bf, biasC[1], 0, 0, 0);
#pragma unroll
        for (int r = 0; r < 16; ++r) {
            // fast 2^(dd+az'): v_fma_f32 + v_cvt_u32_f32 (neg->0) + v_add_f32
            float u0 = fmaf(dd0[r], EXP2_SCALE, az);
            acc[0][r] += __uint_as_float(__float2uint_rz(u0));
            float u1 = fmaf(dd1[r], EXP2_SCALE, az);
            acc[1][r] += __uint_as_float(__float2uint_rz(u1));
        }
    }

    // ---- Epilogue: per-wave transpose-reduce through LDS, one pass per strip.
    __syncthreads();                        // all waves done reading zh
    float* scrw = scr + wave * SCR_WAVE;
#pragma unroll
    for (int s = 0; s < 2; ++s) {
#pragma unroll
        for (int r = 0; r < 16; ++r) {
            const int row = (r & 3) + 8 * (r >> 2) + 4 * hf;
            scrw[row * SCR_STRIDE + ln31] = acc[s][r];   // 2-way max bank alias = free
        }
        // Each lane sums half of row ln31 (16 f32), conflict-free banks (stride 33).
        const float* rp = scrw + ln31 * SCR_STRIDE + hf * 16;
        float sum = 0.f;
#pragma unroll
        for (int j = 0; j < 16; ++j) sum += rp[j];
        sum += __shfl_xor(sum, 32, 64);     // combine the two half-rows
        if (hf == 0)
            atomicAdd(&S[l * MM + m0 + s * 32 + ln31], sum); // device coherence point
        // next pass reuses scrw: DS requests from one wave are processed in order.
    }

    // ---- Last-block-done (NO fence — see header comment for the ordering proof).
    __syncthreads();                 // vmcnt(0) drain: this block's S adds are acked
    if (t == 0) {
        unsigned old = atomicAdd(done_cnt, 1u);
        s_last = (old == GRID - 1) ? 1u : 0u;
    }
    __syncthreads();
    if (s_last) {
        float s = 0.f;
#pragma unroll
        for (int k = 0; k < (NL * MM) / 256; ++k) {
            // agent-scope relaxed atomic load: reads the coherence point the
            // producers' atomicAdds wrote; independent loads, fully pipelined.
            float v = __hip_atomic_load(&S[k * 256 + t], __ATOMIC_RELAXED,
                                        __HIP_MEMORY_SCOPE_AGENT);
            s += __logf(v);
        }
#pragma unroll
        for (int off = 32; off > 0; off >>= 1) s += __shfl_down(s, off, 64);
        if ((t & 63) == 0) red[t >> 6] = s;
        __syncthreads();
        if (t == 0) {
            float tot = red[0] + red[1] + red[2] + red[3];
            out[0] = -tot / (float)(NL * MM)
                   + 32.0f * (2.0f * ls - 1.0f)   // 0.5*z_dim*(2ls-1), z_dim=64
                   + 9.70406052783923f;           // ln(16384)
        }
    }
}

extern "C" void kernel_launch(void* const* d_in, const int* in_sizes, int n_in,
                              void* d_out, int out_size, void* d_ws, size_t ws_size,
                              hipStream_t stream)
{
    const float* z  = (const float*)d_in[0];
    const float* e  = (const float*)d_in[1];
    const float* ls = (const float*)d_in[2];
    float* out = (float*)d_out;
    float* S   = (float*)d_ws;                               // 4096 f32
    unsigned* cnt = (unsigned*)((char*)d_ws + NL * MM * sizeof(float));

    // ws is re-poisoned to 0xAA before every launch; zero S + done-counter.
    hipMemsetAsync(d_ws, 0, NL * MM * sizeof(float) + 64, stream);
    latent_fused_kernel<<<GRID, 256, 0, stream>>>(z, e, ls, S, cnt, out);
}

// Round 10
// 70.053 us; speedup vs baseline: 1.7591x; 1.0593x over previous
//
#include <hip/hip_runtime.h>
#include <math.h>

// Problem constants (fixed by setup_inputs)
#define NL 4          // n_latents
#define MM 1024       // codebook entries per latent
#define DD 16         // dim per latent
#define PP 16384      // points = N*H*W
#define PLANE 1024    // H*W
#define NSTRIDE 65536 // z_dim*H*W
#define CHUNK 256     // points per workgroup (quarter plane)
#define NCHUNK (PP / CHUNK)   // 64
#define MGROUP 256    // codes per workgroup (4 waves x 2 strips x 32)
#define NMG (MM / MGROUP)     // 4
#define ZSTR 20       // LDS stride per point in f16 units (16 data + 4 pad = 40B)
#define SCR_STRIDE 33 // f32 words per row in the transpose-reduce scratch (conflict-free)
#define SCR_WAVE 1056 // 32*33 words per wave region

// Schraudolph-style fast 2^x: bitcast(u32(2^23*(x + B))), B = 127 - 0.0353
// (minimax-centered, max rel err ~±3.5%). x <= 0 always here; negative
// 2^23*(x+B) clamps to 0 via v_cvt_u32_f32 => exact flush-to-zero underflow.
#define EXP2_SCALE 8388608.0f            // 2^23
#define EXP2_BIAS  126.9647f             // 127 - sigma*

typedef _Float16 half4v  __attribute__((ext_vector_type(4)));
typedef _Float16 half8v  __attribute__((ext_vector_type(8)));
typedef float    float16v __attribute__((ext_vector_type(16)));

// r7 configuration — best measured (69.1 us total). Fusion attempts (r4, r8/r9)
// both regressed: last-block tail serializes behind the slowest block; the
// separate 3us reduce node is cheaper. Per-wave __threadfence() is catastrophic
// (r8: 4096 device-scope release fences = +55us) — none used here.
// Per (l, m-group of 256 codes, p-chunk of 256 points); each wave owns 2 strips
// of 32 codes (B-fragment LDS read shared by both MFMAs -> 2x ILP).
//   dd[s] = (m2a2*e_strip_s)(32xK16) . z_tile(K16x32) + biasC[s]  (v_mfma_f32_32x32x16_f16)
//   acc[s][r] += fast_exp2(dd[s][r] + a2*zsq[col])   -- fma/cvt/add, no trans pipe
// Epilogue: per-wave LDS transpose (32x32, stride-33), two sequential passes
// reusing the same wave-private scratch (DS ops per wave are processed in order).
// MFMA 32x32 C/D layout (HW-verified): col=lane&31, row=(reg&3)+8*(reg>>2)+4*(lane>>5)
// A layout (verified rounds 1-9, absmax=0): A[row=lane&31][k=(lane>>5)*8+j]; B same on cols.
__global__ __launch_bounds__(256, 4)
void latent_dist_kernel(const float* __restrict__ z, const float* __restrict__ e,
                        const float* __restrict__ log_sigma, float* __restrict__ S)
{
    const int t    = threadIdx.x;
    const int lane = t & 63;
    const int wave = t >> 6;
    const int ln31 = lane & 31;
    const int hf   = lane >> 5;

    const int bid = blockIdx.x;
    const int c   = bid & (NCHUNK - 1);       // p-chunk (fastest -> mg-sharers 64 apart, same XCD)
    const int mg  = (bid >> 6) & (NMG - 1);   // m-group
    const int l   = bid >> 8;                 // latent

    const float ls    = log_sigma[0];
    const float alpha = -0.5f * __expf(-2.0f * ls);
    const float a2    = alpha * 1.44269504088896340736f; // alpha/ln2
    const float m2a2  = -2.0f * a2;

    // zh (staging, 256*20*2 = 10240B) and scr (transpose-reduce, 4*1056*4 = 16896B)
    // share storage: scr is only used after the main loop's barrier.
    __shared__ __attribute__((aligned(16))) char smem[4 * SCR_WAVE * 4];
    _Float16* zh  = (_Float16*)smem;
    float*    scr = (float*)smem;
    __shared__ float azqs[CHUNK];   // (a2*zsq + EXP2_BIAS) * 2^23  (magic form)
    __shared__ float esqs[MGROUP];

    // ---- Stage z chunk: one point per thread, 16 global f32 (coalesced) -> LDS f16.
    const int n  = c >> 2;                 // 4 chunks per plane
    const int q0 = (c & 3) * CHUNK;
    const float* zb = z + (size_t)n * NSTRIDE + (size_t)l * DD * PLANE + q0;

    float sq = 0.f;
#pragma unroll
    for (int dp = 0; dp < 8; ++dp) {
        float v0 = zb[(2 * dp)     * PLANE + t];
        float v1 = zb[(2 * dp + 1) * PLANE + t];
        sq += v0 * v0 + v1 * v1;
        union { _Float16 h[2]; unsigned u; } pk;
        pk.h[0] = (_Float16)v0; pk.h[1] = (_Float16)v1;
        *(unsigned*)(&zh[t * ZSTR + 2 * dp]) = pk.u; // 4B-aligned packed store
    }
    azqs[t] = (sq * a2 + EXP2_BIAS) * EXP2_SCALE;

    // ---- A fragments for the wave's 2 strips (pre-scaled by m2a2) + exact f32 esq.
    const int m0 = mg * MGROUP + wave * 64;
    half8v Af[2];
#pragma unroll
    for (int s = 0; s < 2; ++s) {
        const float* eb = e + ((size_t)l * MM + m0 + s * 32 + ln31) * DD + hf * 8;
        float4 a0 = *(const float4*)eb;
        float4 a1 = *(const float4*)(eb + 4);
        float esq_p = a0.x*a0.x + a0.y*a0.y + a0.z*a0.z + a0.w*a0.w
                    + a1.x*a1.x + a1.y*a1.y + a1.z*a1.z + a1.w*a1.w;
        esq_p += __shfl_xor(esq_p, 32, 64);       // combine the two k-halves
        esqs[wave * 64 + s * 32 + ln31] = esq_p;  // both halves write same value
        Af[s][0] = (_Float16)(a0.x * m2a2); Af[s][1] = (_Float16)(a0.y * m2a2);
        Af[s][2] = (_Float16)(a0.z * m2a2); Af[s][3] = (_Float16)(a0.w * m2a2);
        Af[s][4] = (_Float16)(a1.x * m2a2); Af[s][5] = (_Float16)(a1.y * m2a2);
        Af[s][6] = (_Float16)(a1.z * m2a2); Af[s][7] = (_Float16)(a1.w * m2a2);
    }

    __syncthreads();

    // C operands = a2*esq[row(r)]: folded into the MFMA, constant over the p-loop.
    float16v biasC[2];
#pragma unroll
    for (int s = 0; s < 2; ++s)
#pragma unroll
        for (int r = 0; r < 16; ++r) {
            const int row = (r & 3) + 8 * (r >> 2) + 4 * hf;
            biasC[s][r] = esqs[wave * 64 + s * 32 + row] * a2;
        }

    float16v acc[2];
#pragma unroll
    for (int s = 0; s < 2; ++s)
#pragma unroll
        for (int r = 0; r < 16; ++r) acc[s][r] = 0.f;

    const _Float16* zrow = zh + ln31 * ZSTR + hf * 8;
#pragma unroll 2
    for (int pt = 0; pt < CHUNK / 32; ++pt) {
        const float az = azqs[pt * 32 + ln31];           // ds_read_b32 (broadcast), magic form
        const _Float16* bp = zrow + pt * 32 * ZSTR;
        half4v b0 = *(const half4v*)bp;                  // ds_read_b64 x2, shared by both strips
        half4v b1 = *(const half4v*)(bp + 4);
        half8v Bf = __builtin_shufflevector(b0, b1, 0, 1, 2, 3, 4, 5, 6, 7);
        float16v dd0 = __builtin_amdgcn_mfma_f32_32x32x16_f16(Af[0], Bf, biasC[0], 0, 0, 0);
        float16v dd1 = __builtin_amdgcn_mfma_f32_32x32x16_f16(Af[1], Bf, biasC[1], 0, 0, 0);
#pragma unroll
        for (int r = 0; r < 16; ++r) {
            // fast 2^(dd+az'): v_fma_f32 + v_cvt_u32_f32 (neg->0) + v_add_f32
            float u0 = fmaf(dd0[r], EXP2_SCALE, az);
            acc[0][r] += __uint_as_float(__float2uint_rz(u0));
            float u1 = fmaf(dd1[r], EXP2_SCALE, az);
            acc[1][r] += __uint_as_float(__float2uint_rz(u1));
        }
    }

    // ---- Epilogue: per-wave transpose-reduce through LDS, one pass per strip.
    __syncthreads();                        // all waves done reading zh
    float* scrw = scr + wave * SCR_WAVE;
#pragma unroll
    for (int s = 0; s < 2; ++s) {
#pragma unroll
        for (int r = 0; r < 16; ++r) {
            const int row = (r & 3) + 8 * (r >> 2) + 4 * hf;
            scrw[row * SCR_STRIDE + ln31] = acc[s][r];   // 2-way max bank alias = free
        }
        // Each lane sums half of row ln31 (16 f32), conflict-free banks (stride 33).
        const float* rp = scrw + ln31 * SCR_STRIDE + hf * 16;
        float sum = 0.f;
#pragma unroll
        for (int j = 0; j < 16; ++j) sum += rp[j];
        sum += __shfl_xor(sum, 32, 64);     // combine the two half-rows
        if (hf == 0)
            atomicAdd(&S[l * MM + m0 + s * 32 + ln31], sum); // 64 adds/address total
        // next pass reuses scrw: DS requests from one wave are processed in order,
        // so pass-2 writes cannot pass pass-1 reads.
    }
}

// Final: log, mean, constants. One workgroup of 1024 reading 16 KB.
__global__ void latent_reduce_kernel(const float* __restrict__ S,
                                     const float* __restrict__ log_sigma,
                                     float* __restrict__ out)
{
    const int t = threadIdx.x;
    float s = 0.f;
#pragma unroll
    for (int k = 0; k < 4; ++k) s += __logf(S[k * 1024 + t]);
#pragma unroll
    for (int off = 32; off > 0; off >>= 1) s += __shfl_down(s, off, 64);
    __shared__ float red[16];
    if ((t & 63) == 0) red[t >> 6] = s;
    __syncthreads();
    if (t == 0) {
        float tot = 0.f;
#pragma unroll
        for (int i = 0; i < 16; ++i) tot += red[i];
        const float ls = log_sigma[0];
        out[0] = -tot / (float)(NL * MM)
               + 32.0f * (2.0f * ls - 1.0f)   // 0.5*z_dim*(2ls-1), z_dim=64
               + 9.70406052783923f;           // ln(16384)
    }
}

extern "C" void kernel_launch(void* const* d_in, const int* in_sizes, int n_in,
                              void* d_out, int out_size, void* d_ws, size_t ws_size,
                              hipStream_t stream)
{
    const float* z  = (const float*)d_in[0];
    const float* e  = (const float*)d_in[1];
    const float* ls = (const float*)d_in[2];
    float* out = (float*)d_out;
    float* S   = (float*)d_ws;

    // ws is re-poisoned to 0xAA before every launch; zero the 16 KB accumulator.
    hipMemsetAsync(S, 0, NL * MM * sizeof(float), stream);
    latent_dist_kernel<<<NL * NMG * NCHUNK, 256, 0, stream>>>(z, e, ls, S);
    latent_reduce_kernel<<<1, 1024, 0, stream>>>(S, ls, out);
}